// Round 1
// baseline (83.366 us; speedup 1.0000x reference)
//
#include <hip/hip_runtime.h>
#include <math.h>

// SafetyLayer: B=8192 batch, R=32 robot links (planar chain), P=16 patient capsules.
// One wave (64 threads) per batch element. FK via wave-level shfl scans,
// seg-seg distances in registers off LDS-staged chain/capsule data.

constexpr int B = 8192;
constexpr int R = 32;
constexpr int P = 16;

#define STEP_SIZE 0.1f
#define D_LIMIT   0.05f
#define EPSV      1e-9f

__global__ __launch_bounds__(64) void safety_layer_kernel(
    const float* __restrict__ joint_state,    // [B,R]
    const float* __restrict__ action_nominal, // [B,R]
    const float* __restrict__ link_lengths,   // [R]
    const float* __restrict__ robot_radii,    // [R]
    const float* __restrict__ p_start,        // [B,P,3]
    const float* __restrict__ p_end,          // [B,P,3]
    const float* __restrict__ p_radii,        // [B,P]
    const float* __restrict__ log_lambda,     // [1]
    float* __restrict__ out)                  // [B*R] action | [B] penalty | [B] min_dist
{
    const int b    = blockIdx.x;
    const int lane = threadIdx.x;

    __shared__ float ptsx[R + 1], ptsy[R + 1];  // chain points (z == 0 always)
    __shared__ float rr[R];
    __shared__ float ps[P * 3], pe[P * 3], pr[P];

    // ---- load per-joint data; lanes 0..31 active ----
    float qn = 0.f, L = 0.f;
    if (lane < R) {
        float js = joint_state[b * R + lane];
        float an = action_nominal[b * R + lane];
        qn = fmaf(an, STEP_SIZE, js);           // q_next
        out[b * R + lane] = an;                 // output 0: passthrough
        L = link_lengths[lane];
        rr[lane] = robot_radii[lane];
    }

    // ---- theta = inclusive cumsum(q_next) over 32 lanes ----
    #pragma unroll
    for (int off = 1; off < 32; off <<= 1) {
        float v = __shfl_up(qn, off, 32);
        if ((lane & 31) >= off) qn += v;
    }
    const float theta = qn;

    // ---- pts = cumsum(L * [cos,sin]) ----
    float cx = L * cosf(theta);
    float cy = L * sinf(theta);
    #pragma unroll
    for (int off = 1; off < 32; off <<= 1) {
        float vx = __shfl_up(cx, off, 32);
        float vy = __shfl_up(cy, off, 32);
        if ((lane & 31) >= off) { cx += vx; cy += vy; }
    }
    if (lane < R) { ptsx[lane + 1] = cx; ptsy[lane + 1] = cy; }
    if (lane == 0) { ptsx[0] = 0.f; ptsy[0] = 0.f; }

    // ---- patient capsules: coalesced 48-float loads ----
    if (lane < P * 3) {
        ps[lane] = p_start[b * P * 3 + lane];
        pe[lane] = p_end[b * P * 3 + lane];
    }
    if (lane < P) pr[lane] = p_radii[b * P + lane];

    __syncthreads();

    // ---- 512 pairs: 64 lanes x 8 iterations ----
    float mind = 1e30f;
    #pragma unroll
    for (int it = 0; it < (R * P) / 64; ++it) {
        const int i = lane + it * 64;
        const int r = i >> 4;   // link index 0..31
        const int p = i & 15;   // patient index 0..15

        const float p1x = ptsx[r],    p1y = ptsy[r];
        const float d1x = ptsx[r + 1] - p1x;
        const float d1y = ptsy[r + 1] - p1y;          // d1z = 0 (planar chain)
        const float p2x = ps[3 * p], p2y = ps[3 * p + 1], p2z = ps[3 * p + 2];
        const float d2x = pe[3 * p]     - p2x;
        const float d2y = pe[3 * p + 1] - p2y;
        const float d2z = pe[3 * p + 2] - p2z;
        const float rx = p1x - p2x, ry = p1y - p2y, rz = -p2z;

        const float a  = d1x * d1x + d1y * d1y;
        const float e  = d2x * d2x + d2y * d2y + d2z * d2z;
        const float f  = d2x * rx + d2y * ry + d2z * rz;
        const float c  = d1x * rx + d1y * ry;
        const float bb = d1x * d2x + d1y * d2y;

        const float denom = a * e - bb * bb;
        float s = 0.f;
        if (denom > EPSV) {
            s = (bb * f - c * e) / denom;              // max(denom,EPS)==denom here
            s = fminf(fmaxf(s, 0.f), 1.f);
        }
        float t = 0.f;
        if (e > EPSV) t = (bb * s + f) / e;            // max(e,EPS)==e here
        const float t_c = fminf(fmaxf(t, 0.f), 1.f);
        if (t != t_c) {                                // reference re-clamp path
            s = 0.f;
            if (a > EPSV) {
                s = (bb * t_c - c) / a;
                s = fminf(fmaxf(s, 0.f), 1.f);
            }
        }

        const float c1x = fmaf(d1x, s, p1x), c1y = fmaf(d1y, s, p1y);
        const float c2x = fmaf(d2x, t_c, p2x), c2y = fmaf(d2y, t_c, p2y), c2z = fmaf(d2z, t_c, p2z);
        const float fx = c1x - c2x, fy = c1y - c2y, fz = -c2z;
        const float d = sqrtf(fx * fx + fy * fy + fz * fz + 1e-12f);

        mind = fminf(mind, d - (rr[r] + pr[p]));
    }

    // ---- min-reduce across the full wave (64 lanes) ----
    #pragma unroll
    for (int off = 32; off >= 1; off >>= 1)
        mind = fminf(mind, __shfl_xor(mind, off));

    if (lane == 0) {
        const float lam = expf(log_lambda[0]);
        const float pen = (mind < D_LIMIT) ? lam * (D_LIMIT - mind) : 0.f;
        out[B * R + b]     = pen;      // output 1: penalty
        out[B * R + B + b] = mind;     // output 2: min_dist
    }
}

extern "C" void kernel_launch(void* const* d_in, const int* in_sizes, int n_in,
                              void* d_out, int out_size, void* d_ws, size_t ws_size,
                              hipStream_t stream) {
    const float* joint_state    = (const float*)d_in[0];
    const float* action_nominal = (const float*)d_in[1];
    const float* link_lengths   = (const float*)d_in[2];
    const float* robot_radii    = (const float*)d_in[3];
    const float* p_start        = (const float*)d_in[4];
    const float* p_end          = (const float*)d_in[5];
    const float* p_radii        = (const float*)d_in[6];
    const float* log_lambda     = (const float*)d_in[7];
    float* out = (float*)d_out;

    safety_layer_kernel<<<B, 64, 0, stream>>>(
        joint_state, action_nominal, link_lengths, robot_radii,
        p_start, p_end, p_radii, log_lambda, out);
}

// Round 2
// 78.498 us; speedup vs baseline: 1.0620x; 1.0620x over previous
//
#include <hip/hip_runtime.h>
#include <math.h>

// SafetyLayer: B=8192 batch, R=32 robot links (planar chain), P=16 patient capsules.
// 4 waves per block (256 thr), one wave per batch element. FK via shfl scans,
// HW transcendentals (v_sin/v_cos/v_rcp/v_sqrt) -- threshold is 8.9e-2, abs err
// from fast paths is ~3e-5. Wave-private LDS slices.

constexpr int B   = 8192;
constexpr int R   = 32;
constexpr int P   = 16;
constexpr int WPB = 4;   // waves per block

#define STEP_SIZE 0.1f
#define D_LIMIT   0.05f
#define EPSV      1e-9f

__device__ __forceinline__ float frcp(float x)  { return __builtin_amdgcn_rcpf(x); }
__device__ __forceinline__ float fsqrt(float x) { return __builtin_amdgcn_sqrtf(x); }

__global__ __launch_bounds__(WPB * 64) void safety_layer_kernel(
    const float* __restrict__ joint_state,    // [B,R]
    const float* __restrict__ action_nominal, // [B,R]
    const float* __restrict__ link_lengths,   // [R]
    const float* __restrict__ robot_radii,    // [R]
    const float* __restrict__ p_start,        // [B,P,3]
    const float* __restrict__ p_end,          // [B,P,3]
    const float* __restrict__ p_radii,        // [B,P]
    const float* __restrict__ log_lambda,     // [1]
    float* __restrict__ out)                  // [B*R] action | [B] penalty | [B] min_dist
{
    const int w    = threadIdx.x >> 6;
    const int lane = threadIdx.x & 63;
    const int b    = blockIdx.x * WPB + w;

    __shared__ float ptsx[WPB][R + 1], ptsy[WPB][R + 1];
    __shared__ float rr[WPB][R];
    __shared__ float ps[WPB][P * 3], pe[WPB][P * 3], pr[WPB][P];

    // ---- per-joint loads; lanes 0..31 of each wave ----
    float qn = 0.f, L = 0.f;
    if (lane < R) {
        float js = joint_state[b * R + lane];
        float an = action_nominal[b * R + lane];
        qn = fmaf(an, STEP_SIZE, js);           // q_next
        out[b * R + lane] = an;                 // output 0: passthrough
        L = link_lengths[lane];
        rr[w][lane] = robot_radii[lane];
    }

    // ---- theta = inclusive cumsum(q_next) over 32 lanes ----
    #pragma unroll
    for (int off = 1; off < 32; off <<= 1) {
        float v = __shfl_up(qn, off, 32);
        if ((lane & 31) >= off) qn += v;
    }
    const float theta = qn;

    // ---- pts = cumsum(L * [cos,sin]) ; HW sin/cos (|theta| < ~30 rad, safe) ----
    float cx = L * __cosf(theta);
    float cy = L * __sinf(theta);
    #pragma unroll
    for (int off = 1; off < 32; off <<= 1) {
        float vx = __shfl_up(cx, off, 32);
        float vy = __shfl_up(cy, off, 32);
        if ((lane & 31) >= off) { cx += vx; cy += vy; }
    }
    if (lane < R) { ptsx[w][lane + 1] = cx; ptsy[w][lane + 1] = cy; }
    if (lane == 0) { ptsx[w][0] = 0.f; ptsy[w][0] = 0.f; }

    // ---- patient capsules: coalesced loads ----
    if (lane < P * 3) {
        ps[w][lane] = p_start[b * P * 3 + lane];
        pe[w][lane] = p_end[b * P * 3 + lane];
    }
    if (lane < P) pr[w][lane] = p_radii[b * P + lane];

    __syncthreads();

    // ---- 512 pairs: 64 lanes x 8 iterations ----
    float mind = 1e30f;
    #pragma unroll
    for (int it = 0; it < (R * P) / 64; ++it) {
        const int i = lane + it * 64;
        const int r = i >> 4;   // link index 0..31
        const int p = i & 15;   // patient index 0..15

        const float p1x = ptsx[w][r],    p1y = ptsy[w][r];
        const float d1x = ptsx[w][r + 1] - p1x;
        const float d1y = ptsy[w][r + 1] - p1y;        // d1z = 0 (planar chain)
        const float p2x = ps[w][3 * p], p2y = ps[w][3 * p + 1], p2z = ps[w][3 * p + 2];
        const float d2x = pe[w][3 * p]     - p2x;
        const float d2y = pe[w][3 * p + 1] - p2y;
        const float d2z = pe[w][3 * p + 2] - p2z;
        const float rx = p1x - p2x, ry = p1y - p2y, rz = -p2z;

        const float a  = d1x * d1x + d1y * d1y;
        const float e  = d2x * d2x + d2y * d2y + d2z * d2z;
        const float f  = d2x * rx + d2y * ry + d2z * rz;
        const float c  = d1x * rx + d1y * ry;
        const float bb = d1x * d2x + d1y * d2y;

        const float denom = a * e - bb * bb;
        float s = 0.f;
        if (denom > EPSV) {
            s = (bb * f - c * e) * frcp(denom);
            s = fminf(fmaxf(s, 0.f), 1.f);
        }
        float t = 0.f;
        if (e > EPSV) t = (bb * s + f) * frcp(e);
        const float t_c = fminf(fmaxf(t, 0.f), 1.f);
        if (t < 0.f || t > 1.f) {                      // reference re-clamp path
            s = 0.f;
            if (a > EPSV) {
                s = (bb * t_c - c) * frcp(a);
                s = fminf(fmaxf(s, 0.f), 1.f);
            }
        }

        const float c1x = fmaf(d1x, s, p1x), c1y = fmaf(d1y, s, p1y);
        const float c2x = fmaf(d2x, t_c, p2x), c2y = fmaf(d2y, t_c, p2y), c2z = fmaf(d2z, t_c, p2z);
        const float fx = c1x - c2x, fy = c1y - c2y, fz = -c2z;
        const float d = fsqrt(fx * fx + fy * fy + fz * fz + 1e-12f);

        mind = fminf(mind, d - (rr[w][r] + pr[w][p]));
    }

    // ---- min-reduce across the wave (64 lanes) ----
    #pragma unroll
    for (int off = 32; off >= 1; off >>= 1)
        mind = fminf(mind, __shfl_xor(mind, off));

    if (lane == 0) {
        const float lam = __expf(log_lambda[0]);
        const float pen = (mind < D_LIMIT) ? lam * (D_LIMIT - mind) : 0.f;
        out[B * R + b]     = pen;      // output 1: penalty
        out[B * R + B + b] = mind;     // output 2: min_dist
    }
}

extern "C" void kernel_launch(void* const* d_in, const int* in_sizes, int n_in,
                              void* d_out, int out_size, void* d_ws, size_t ws_size,
                              hipStream_t stream) {
    const float* joint_state    = (const float*)d_in[0];
    const float* action_nominal = (const float*)d_in[1];
    const float* link_lengths   = (const float*)d_in[2];
    const float* robot_radii    = (const float*)d_in[3];
    const float* p_start        = (const float*)d_in[4];
    const float* p_end          = (const float*)d_in[5];
    const float* p_radii        = (const float*)d_in[6];
    const float* log_lambda     = (const float*)d_in[7];
    float* out = (float*)d_out;

    safety_layer_kernel<<<B / WPB, WPB * 64, 0, stream>>>(
        joint_state, action_nominal, link_lengths, robot_radii,
        p_start, p_end, p_radii, log_lambda, out);
}